// Round 2
// baseline (489.847 us; speedup 1.0000x reference)
//
#include <hip/hip_runtime.h>

// StyleGAN 3D upsample x2, k=[1,4,6,4,1]/16*2 per axis, fused polyphase:
//   even: o[2i]   = 0.5*(x[i-1]+x[i])
//   odd : o[2i+1] = 0.125*x[i-1] + 0.75*x[i] + 0.125*x[i+1]
// Input fp32 [4,32,48,48,48], output fp32 [4,32,96,96,96].

#define IN_D 48
#define IN_H 48
#define IN_W 48
#define NC   128            // N*C = 4*32
#define TD   8              // input tile depth per block
#define TH   16             // input tile height per block (== blockDim.y)
#define TW   16             // input tile width per block  (== blockDim.x)
#define LZ   (TD + 2)       // 10  (halo)
#define LY   (TH + 2)       // 18
#define LX   (TW + 2)       // 18
#define LXP  (LX + 1)       // 19  padded LDS row stride (bank-conflict break)

__global__ __launch_bounds__(TW * TH)
void upfir3d_kernel(const float* __restrict__ in,
                    float* __restrict__ out) {
    __shared__ float lds[LZ * LY * LXP];   // 10*18*19*4 = 13680 B

    const int tx = threadIdx.x;            // W within tile
    const int ty = threadIdx.y;            // H within tile
    const int bw = blockIdx.x;             // 0..2
    const int bh = blockIdx.y;             // 0..2
    const int bz = blockIdx.z;             // 0..(6*128-1)
    const int dz = bz % (IN_D / TD);       // 0..5
    const int nc = bz / (IN_D / TD);       // 0..127

    const int iw0 = bw * TW;
    const int ih0 = bh * TH;
    const int id0 = dz * TD;
    const size_t in_base = (size_t)nc * (IN_D * IN_H * IN_W);

    // ---- stage halo tile into LDS, zero outside input bounds ----
    const int tid = ty * TW + tx;
    for (int idx = tid; idx < LZ * LY * LX; idx += TW * TH) {
        int z   = idx / (LY * LX);
        int rem = idx - z * (LY * LX);
        int y   = rem / LX;
        int xx  = rem - y * LX;
        int gd = id0 - 1 + z;
        int gh = ih0 - 1 + y;
        int gw = iw0 - 1 + xx;
        float v = 0.0f;
        if ((unsigned)gd < (unsigned)IN_D && (unsigned)gh < (unsigned)IN_H &&
            (unsigned)gw < (unsigned)IN_W) {
            v = in[in_base + ((size_t)gd * IN_H + gh) * IN_W + gw];
        }
        lds[(z * LY + y) * LXP + xx] = v;
    }
    __syncthreads();

    // ---- per-thread: one (iw,ih) input column, slide along D ----
    const int lx = tx + 1;                 // LDS coords of the center cell
    const int ly = ty + 1;

    // WH-combined phase partials for one LDS layer z:
    //   returns {hpE_wpE, hpE_wpO, hpO_wpE, hpO_wpO}
    auto whpart = [&](int z) -> float4 {
        const float* p = &lds[(z * LY + (ly - 1)) * LXP + (lx - 1)];
        float rE[3], rO[3];
#pragma unroll
        for (int dy = 0; dy < 3; ++dy) {
            float v0 = p[dy * LXP + 0];
            float v1 = p[dy * LXP + 1];
            float v2 = p[dy * LXP + 2];
            rE[dy] = 0.5f * (v0 + v1);
            rO[dy] = 0.125f * (v0 + v2) + 0.75f * v1;
        }
        float4 q;
        q.x = 0.5f * (rE[0] + rE[1]);                    // oh even, ow even
        q.y = 0.5f * (rO[0] + rO[1]);                    // oh even, ow odd
        q.z = 0.125f * (rE[0] + rE[2]) + 0.75f * rE[1];  // oh odd,  ow even
        q.w = 0.125f * (rO[0] + rO[2]) + 0.75f * rO[1];  // oh odd,  ow odd
        return q;
    };

    float4 qm = whpart(0);   // layer id0-1
    float4 qc = whpart(1);   // layer id0

    const int OD = 2 * IN_D, OH = 2 * IN_H, OW = 2 * IN_W;
    const int ow = 2 * (iw0 + tx);
    const int oh = 2 * (ih0 + ty);
    float* obase = out + (size_t)nc * OD * OH * OW;

    auto store_rows = [&](int od_, float4 v) {
        size_t base = ((size_t)od_ * OH + oh) * OW + ow;
        float2 r0 = make_float2(v.x, v.y);   // row oh   : (ow even, ow odd)
        float2 r1 = make_float2(v.z, v.w);   // row oh+1
        *reinterpret_cast<float2*>(obase + base)      = r0;
        *reinterpret_cast<float2*>(obase + base + OW) = r1;
    };

#pragma unroll
    for (int d = 0; d < TD; ++d) {
        float4 qp = whpart(d + 2);        // layer id0+d+1
        int od = 2 * (id0 + d);

        float4 e, o;
        e.x = 0.5f * (qm.x + qc.x);
        e.y = 0.5f * (qm.y + qc.y);
        e.z = 0.5f * (qm.z + qc.z);
        e.w = 0.5f * (qm.w + qc.w);
        o.x = 0.125f * (qm.x + qp.x) + 0.75f * qc.x;
        o.y = 0.125f * (qm.y + qp.y) + 0.75f * qc.y;
        o.z = 0.125f * (qm.z + qp.z) + 0.75f * qc.z;
        o.w = 0.125f * (qm.w + qp.w) + 0.75f * qc.w;

        store_rows(od,     e);            // od even
        store_rows(od + 1, o);            // od odd

        qm = qc;
        qc = qp;
    }
}

extern "C" void kernel_launch(void* const* d_in, const int* in_sizes, int n_in,
                              void* d_out, int out_size, void* d_ws, size_t ws_size,
                              hipStream_t stream) {
    const float* x = (const float*)d_in[0];
    float* out = (float*)d_out;

    dim3 grid(IN_W / TW, IN_H / TH, (IN_D / TD) * NC);   // (3, 3, 768)
    dim3 block(TW, TH, 1);                               // 256 threads
    upfir3d_kernel<<<grid, block, 0, stream>>>(x, out);
}